// Round 15
// baseline (26.552 us; speedup 1.0000x reference)
//
#include <hip/hip_runtime.h>
#include <cstdint>

// Flux_Kernels: 5-point stencil with Dirichlet BCs on all 4 sides.
// out[i,j] = D * ( s0*(nUp + nDown + nLeft + nRight) + 4*s1*u[i,j] )
// Off-grid neighbors -> dirichlet_val[{0,1,2,3}] for {i=0, i=NX-1, j=0, j=NY-1}.
//
// Round-15: persistent double-buffered chunks + counted vmcnt (T3/T4).
// R12-14's single-shot tiles end each stage with __syncthreads = vmcnt(0)
// drain -> stage/compute serialize. Here each block owns 128 rows = 4 chunks
// of 32; while computing chunk t from buf[t&1], chunk t+1's global_load_lds
// DMA is in flight into buf[(t+1)&1]. Per chunk each wave issues EXACTLY
// 9 DMA ops (rows k=w,w+4,..<34 -> 9/9/8/8, + halo-column DMA on waves 2/3)
// and EXACTLY 8 b128 stores, so the counted waits are compile-time exact:
//   steady state: wait vmcnt(17) (= 8 stores + 9 newer DMAs), never 0.
// Raw s_barrier (no implicit drain); lgkmcnt(0) barrier before buffer reuse.
// Halo scalars staged via width-4 per-lane-address DMA (global source IS
// per-lane; LDS dest = base + lane*4). 512 blocks (2/CU, LDS 72.8 KB) =
// exactly one resident generation, no dispatch tail.

#define NX 4096
#define NY 4096
#define TR 32                  // output rows per chunk
#define HR (TR + 2)            // staged rows per chunk
#define TC 256                 // cols per block
#define LSTRIDE 264            // LDS row stride in floats
#define HOFF (HR * LSTRIDE)    // left-halo array base (floats); right at +64
#define BUF_FLOATS (HOFF + 128)
#define CHUNKS 4

typedef float float4v __attribute__((ext_vector_type(4)));

__device__ __forceinline__ void row_to_lds(const float* g, float* l) {
    __builtin_amdgcn_global_load_lds(
        (const __attribute__((address_space(1))) uint32_t*)g,
        (__attribute__((address_space(3))) uint32_t*)l, 16, 0, 0);
}
__device__ __forceinline__ void sc_to_lds(const float* g, float* l) {
    __builtin_amdgcn_global_load_lds(
        (const __attribute__((address_space(1))) uint32_t*)g,
        (__attribute__((address_space(3))) uint32_t*)l, 4, 0, 0);
}

#define WAIT_VM(NSTR) { asm volatile("s_waitcnt vmcnt(" NSTR ")" ::: "memory"); \
                        __builtin_amdgcn_sched_barrier(0); }
#define WAIT_LGKM0    { asm volatile("s_waitcnt lgkmcnt(0)" ::: "memory");      \
                        __builtin_amdgcn_sched_barrier(0); }
#define BAR           __builtin_amdgcn_s_barrier();

__global__ __launch_bounds__(256, 2) void flux_stencil_kernel(
    const float* __restrict__ u,
    const float* __restrict__ D_eff,
    const float* __restrict__ dv,
    const float* __restrict__ st,
    float* __restrict__ out)
{
    __shared__ float s[2][BUF_FLOATS];   // 2 x 36,416 B = 72,832 B

    const float D  = D_eff[0];
    const float s0 = st[0];
    const float s1 = st[1];
    const float k1 = D * s0;
    const float k4 = 4.0f * D * s1;
    const float dvUp = dv[0], dvDn = dv[1], dvL = dv[2], dvR = dv[3];

    // 512 blocks: XCD X owns bands [4X,4X+4) (rows [512X,512X+512)), 16 col-tiles.
    const int b    = blockIdx.x;           // [0,512)
    const int X    = b & 7;
    const int r    = b >> 3;               // [0,64)
    const int ct   = r & 15;
    const int band = X * 4 + (r >> 4);     // [0,32)
    const int j0   = ct * TC;
    const int i0b  = band * (TR * CHUNKS); // first row of this block's 128

    const int t    = threadIdx.x;
    const int w    = t >> 6;
    const int lane = t & 63;

    const bool lEdgeCol = (j0 == 0);
    const bool rEdgeCol = (j0 + TC == NY);

    // ---- stage chunk (9 DMA instructions per wave, exact) ----
    #define STAGE(m)                                                           \
    {                                                                          \
        float* sb = s[(m) & 1];                                                \
        const int i0 = i0b + (m) * TR;                                         \
        for (int k = w; k < HR; k += 4) {          /* 9/9/8/8 rows */          \
            int gr = i0 + k - 1;                                               \
            gr = gr < 0 ? 0 : (gr > NX - 1 ? NX - 1 : gr);                     \
            row_to_lds(u + (size_t)gr * NY + j0 + 4 * lane, sb + k * LSTRIDE); \
        }                                                                      \
        if (w == 2) {                              /* left halo col */         \
            const int gr  = i0 + (lane < TR ? lane : TR - 1);                  \
            const int col = lEdgeCol ? 0 : j0 - 1;                             \
            sc_to_lds(u + (size_t)gr * NY + col, sb + HOFF);                   \
        }                                                                      \
        if (w == 3) {                              /* right halo col */        \
            const int gr  = i0 + (lane < TR ? lane : TR - 1);                  \
            const int col = rEdgeCol ? NY - 1 : j0 + TC;                       \
            sc_to_lds(u + (size_t)gr * NY + col, sb + HOFF + 64);              \
        }                                                                      \
    }

    // ---- compute chunk (8 b128 stores per wave, exact) ----
    #define COMPUTE(m)                                                         \
    {                                                                          \
        const float* sb = s[(m) & 1];                                          \
        const int i0 = i0b + (m) * TR;                                         \
        const bool topE = (band == 0)  && ((m) == 0);                          \
        const bool botE = (band == 31) && ((m) == CHUNKS - 1);                 \
        const int cOff = 4 * lane;                                             \
        const int lOff = (lane == 0) ? 0 : cOff - 4;                           \
        const int rOff = cOff + 4;               /* lane63: pad, selected */   \
        _Pragma("unroll")                                                      \
        for (int rr8 = 0; rr8 < 8; ++rr8) {                                    \
            const int rr = w * 8 + rr8;          /* row in chunk [0,32) */     \
            const int k  = rr + 1;                                             \
            const float* rowc = sb + k * LSTRIDE;                              \
            float4v up = *(const float4v*)(sb + (k - 1) * LSTRIDE + cOff);     \
            float4v c  = *(const float4v*)(rowc + cOff);                       \
            float4v dn = *(const float4v*)(sb + (k + 1) * LSTRIDE + cOff);     \
            const float4v lv = *(const float4v*)(rowc + lOff);                 \
            const float4v rv = *(const float4v*)(rowc + rOff);                 \
            const float hl = sb[HOFF + rr];       /* broadcast read */         \
            const float hr = sb[HOFF + 64 + rr];                               \
            const float lft = (lane == 0)  ? (lEdgeCol ? dvL : hl) : lv.w;     \
            const float rgt = (lane == 63) ? (rEdgeCol ? dvR : hr) : rv.x;     \
            if (topE && rr == 0)      { up.x=dvUp; up.y=dvUp; up.z=dvUp; up.w=dvUp; } \
            if (botE && rr == TR - 1) { dn.x=dvDn; dn.y=dvDn; dn.z=dvDn; dn.w=dvDn; } \
            float4v o;                                                         \
            o.x = k1 * (up.x + dn.x + lft + c.y) + k4 * c.x;                   \
            o.y = k1 * (up.y + dn.y + c.x + c.z) + k4 * c.y;                   \
            o.z = k1 * (up.z + dn.z + c.y + c.w) + k4 * c.z;                   \
            o.w = k1 * (up.w + dn.w + c.z + rgt) + k4 * c.w;                   \
            *(float4v*)(out + (size_t)(i0 + rr) * NY + j0 + cOff) = o;         \
        }                                                                      \
    }

    // ---- pipeline ----
    STAGE(0)                         // 9 DMA
    STAGE(1)                         // 9 DMA
    WAIT_VM("9")  BAR                // chunk0 landed (newest 9 = chunk1 DMA)
    COMPUTE(0)                       // 8 stores
    WAIT_LGKM0    BAR                // buf0 reads done -> reusable
    STAGE(2)                         // 9 DMA into buf0
    WAIT_VM("17") BAR                // chunk1 landed (newest 17 = 8 st + 9 DMA)
    COMPUTE(1)
    WAIT_LGKM0    BAR
    STAGE(3)
    WAIT_VM("17") BAR                // chunk2 landed
    COMPUTE(2)
    WAIT_VM("8")  BAR                // chunk3 landed (newest 8 = stores of c2)
    COMPUTE(3)

    #undef STAGE
    #undef COMPUTE
}

extern "C" void kernel_launch(void* const* d_in, const int* in_sizes, int n_in,
                              void* d_out, int out_size, void* d_ws, size_t ws_size,
                              hipStream_t stream) {
    const float* u_main    = (const float*)d_in[0];
    // d_in[1] = u_coupled (unused)
    const float* D_eff     = (const float*)d_in[2];
    const float* dirichlet = (const float*)d_in[3];
    const float* stencil   = (const float*)d_in[4];
    // d_in[5] = t (unused)
    float* outp = (float*)d_out;

    // 32 bands (128 rows each) x 16 col-tiles = 512 blocks, 2/CU
    const int grid  = 512;
    const int block = 256;

    flux_stencil_kernel<<<grid, block, 0, stream>>>(u_main, D_eff, dirichlet, stencil, outp);
}

// Round 16
// 25.523 us; speedup vs baseline: 1.0403x; 1.0403x over previous
//
#include <hip/hip_runtime.h>
#include <cstdint>

// Flux_Kernels: 5-point stencil with Dirichlet BCs on all 4 sides.
// out[i,j] = D * ( s0*(nUp + nDown + nLeft + nRight) + 4*s1*u[i,j] )
// Off-grid neighbors -> dirichlet_val[{0,1,2,3}] for {i=0, i=NX-1, j=0, j=NY-1}.
//
// Round-16: R15's double-buffered counted-vmcnt pipeline WITHOUT the
// occupancy cost. R15 at 2 blocks/CU regressed (26.6us): the intra-block
// pipeline couldn't replace the cross-block overlap that 4-8 blocks/CU gave
// R12-R14 for free. Here TR=16 -> 39KB LDS -> 4 blocks/CU (R14's occupancy)
// AND chunk t+1's DMA stays in flight across compute of chunk t.
// Exact per-wave VMEM counts per chunk: 5 DMA (rows 5/5/4/4 + halo-col DMA
// on waves 2/3) and 4 b128 stores -> waits are compile-time exact:
// vmcnt(5) prologue, vmcnt(9) steady (4 st + 5 newer DMA), vmcnt(4) tail.
// Compute = R14's rolling 3-read-per-row (conflict-free shifted b128).

#define NX 4096
#define NY 4096
#define TR 16                  // output rows per chunk
#define HR (TR + 2)            // staged rows per chunk
#define TC 256                 // cols per block
#define LSTRIDE 264            // LDS row stride in floats
#define HOFF (HR * LSTRIDE)    // halo arrays base; left at +0, right at +64
#define BUF_FLOATS (HOFF + 128)
#define CHUNKS 4               // rows per block = 64

typedef float float4v __attribute__((ext_vector_type(4)));

__device__ __forceinline__ void row_to_lds(const float* g, float* l) {
    __builtin_amdgcn_global_load_lds(
        (const __attribute__((address_space(1))) uint32_t*)g,
        (__attribute__((address_space(3))) uint32_t*)l, 16, 0, 0);
}
__device__ __forceinline__ void sc_to_lds(const float* g, float* l) {
    __builtin_amdgcn_global_load_lds(
        (const __attribute__((address_space(1))) uint32_t*)g,
        (__attribute__((address_space(3))) uint32_t*)l, 4, 0, 0);
}

#define WAIT_VM(NSTR) { asm volatile("s_waitcnt vmcnt(" NSTR ")" ::: "memory"); \
                        __builtin_amdgcn_sched_barrier(0); }
#define WAIT_LGKM0    { asm volatile("s_waitcnt lgkmcnt(0)" ::: "memory");      \
                        __builtin_amdgcn_sched_barrier(0); }
#define BAR           __builtin_amdgcn_s_barrier();

__global__ __launch_bounds__(256, 4) void flux_stencil_kernel(
    const float* __restrict__ u,
    const float* __restrict__ D_eff,
    const float* __restrict__ dv,
    const float* __restrict__ st,
    float* __restrict__ out)
{
    __shared__ float s[2][BUF_FLOATS];   // 2 x 19,520 B = 39,040 B

    const float D  = D_eff[0];
    const float s0 = st[0];
    const float s1 = st[1];
    const float k1 = D * s0;
    const float k4 = 4.0f * D * s1;
    const float dvUp = dv[0], dvDn = dv[1], dvL = dv[2], dvR = dv[3];

    // 1024 blocks: XCD X owns bands [8X,8X+8) (rows [512X,512X+512)).
    const int b    = blockIdx.x;           // [0,1024)
    const int X    = b & 7;
    const int r    = b >> 3;               // [0,128)
    const int ct   = r & 15;               // col-tile [0,16)
    const int band = X * 8 + (r >> 4);     // [0,64)
    const int j0   = ct * TC;
    const int i0b  = band * (TR * CHUNKS); // first of this block's 64 rows

    const int t    = threadIdx.x;
    const int w    = t >> 6;
    const int lane = t & 63;

    const bool lEdgeCol = (j0 == 0);
    const bool rEdgeCol = (j0 + TC == NY);

    // ---- stage chunk m: exactly 5 DMA per wave ----
    #define STAGE(m)                                                           \
    {                                                                          \
        float* sb = s[(m) & 1];                                                \
        const int i0 = i0b + (m) * TR;                                         \
        for (int k = w; k < HR; k += 4) {          /* 5/5/4/4 rows */          \
            int gr = i0 + k - 1;                                               \
            gr = gr < 0 ? 0 : (gr > NX - 1 ? NX - 1 : gr);                     \
            row_to_lds(u + (size_t)gr * NY + j0 + 4 * lane, sb + k * LSTRIDE); \
        }                                                                      \
        if (w == 2) {                              /* left halo col */         \
            const int gr  = i0 + (lane < TR ? lane : TR - 1);                  \
            const int col = lEdgeCol ? 0 : j0 - 1;                             \
            sc_to_lds(u + (size_t)gr * NY + col, sb + HOFF);                   \
        }                                                                      \
        if (w == 3) {                              /* right halo col */        \
            const int gr  = i0 + (lane < TR ? lane : TR - 1);                  \
            const int col = rEdgeCol ? NY - 1 : j0 + TC;                       \
            sc_to_lds(u + (size_t)gr * NY + col, sb + HOFF + 64);              \
        }                                                                      \
    }

    // ---- compute chunk m: rolling 3-read rows, exactly 4 stores per wave ----
    #define COMPUTE(m)                                                         \
    {                                                                          \
        const float* sb = s[(m) & 1];                                          \
        const int i0 = i0b + (m) * TR;                                         \
        const bool topE = (band == 0)  && ((m) == 0);                          \
        const bool botE = (band == 63) && ((m) == CHUNKS - 1);                 \
        const int cOff = 4 * lane;                                             \
        const int lOff = (lane == 0) ? 0 : cOff - 4;   /* lane0: dummy */      \
        const int rOff = cOff + 4;                     /* lane63: pad */       \
        const int rrB  = w * 4;                        /* first row of wave */ \
        const int kB   = rrB + 1;                      /* its LDS row */       \
        float4v up = *(const float4v*)(sb + (kB - 1) * LSTRIDE + cOff);        \
        float4v c  = *(const float4v*)(sb + kB * LSTRIDE + cOff);              \
        const float4v lv0 = *(const float4v*)(sb + kB * LSTRIDE + lOff);       \
        const float4v rv0 = *(const float4v*)(sb + kB * LSTRIDE + rOff);       \
        float lft = (lane == 0)  ? (lEdgeCol ? dvL : sb[HOFF + rrB])      : lv0.w; \
        float rgt = (lane == 63) ? (rEdgeCol ? dvR : sb[HOFF + 64 + rrB]) : rv0.x; \
        if (topE && w == 0) { up.x = dvUp; up.y = dvUp; up.z = dvUp; up.w = dvUp; } \
        _Pragma("unroll")                                                      \
        for (int rr4 = 0; rr4 < 4; ++rr4) {                                    \
            const int rr = rrB + rr4;                  /* row in chunk */      \
            const int k  = rr + 1;                                             \
            const float* nrow = sb + (k + 1) * LSTRIDE;                        \
            float4v dn        = *(const float4v*)(nrow + cOff);                \
            const float4v dnl = *(const float4v*)(nrow + lOff);                \
            const float4v dnr = *(const float4v*)(nrow + rOff);                \
            if (botE && rr == TR - 1) { dn.x=dvDn; dn.y=dvDn; dn.z=dvDn; dn.w=dvDn; } \
            float4v o;                                                         \
            o.x = k1 * (up.x + dn.x + lft + c.y) + k4 * c.x;                   \
            o.y = k1 * (up.y + dn.y + c.x + c.z) + k4 * c.y;                   \
            o.z = k1 * (up.z + dn.z + c.y + c.w) + k4 * c.z;                   \
            o.w = k1 * (up.w + dn.w + c.z + rgt) + k4 * c.w;                   \
            *(float4v*)(out + (size_t)(i0 + rr) * NY + j0 + cOff) = o;         \
            up  = c;                                                           \
            c   = dn;                                                          \
            lft = (lane == 0)  ? (lEdgeCol ? dvL : sb[HOFF + rr + 1])      : dnl.w; \
            rgt = (lane == 63) ? (rEdgeCol ? dvR : sb[HOFF + 64 + rr + 1]) : dnr.x; \
        }                                                                      \
    }

    // ---- pipeline: DMA of chunk t+1 in flight across compute of chunk t ----
    STAGE(0)                         // 5 DMA
    STAGE(1)                         // 5 DMA
    WAIT_VM("5")  BAR                // chunk0 landed (5 newest = chunk1 DMA)
    COMPUTE(0)                       // 4 stores
    WAIT_LGKM0    BAR                // buf0 reads done -> reusable
    STAGE(2)                         // 5 DMA into buf0
    WAIT_VM("9")  BAR                // chunk1 landed (newest 9 = 4 st + 5 DMA)
    COMPUTE(1)
    WAIT_LGKM0    BAR
    STAGE(3)
    WAIT_VM("9")  BAR                // chunk2 landed
    COMPUTE(2)
    WAIT_VM("4")  BAR                // chunk3 landed (newest 4 = stores of c2)
    COMPUTE(3)

    #undef STAGE
    #undef COMPUTE
}

extern "C" void kernel_launch(void* const* d_in, const int* in_sizes, int n_in,
                              void* d_out, int out_size, void* d_ws, size_t ws_size,
                              hipStream_t stream) {
    const float* u_main    = (const float*)d_in[0];
    // d_in[1] = u_coupled (unused)
    const float* D_eff     = (const float*)d_in[2];
    const float* dirichlet = (const float*)d_in[3];
    const float* stencil   = (const float*)d_in[4];
    // d_in[5] = t (unused)
    float* outp = (float*)d_out;

    // 64 bands (64 rows each) x 16 col-tiles = 1024 blocks, 4/CU
    const int grid  = 1024;
    const int block = 256;

    flux_stencil_kernel<<<grid, block, 0, stream>>>(u_main, D_eff, dirichlet, stencil, outp);
}

// Round 17
// 24.666 us; speedup vs baseline: 1.0764x; 1.0347x over previous
//
#include <hip/hip_runtime.h>
#include <cstdint>

// Flux_Kernels: 5-point stencil with Dirichlet BCs on all 4 sides.
// out[i,j] = D * ( s0*(nUp + nDown + nLeft + nRight) + 4*s1*u[i,j] )
// Off-grid neighbors -> dirichlet_val[{0,1,2,3}] for {i=0, i=NX-1, j=0, j=NY-1}.
//
// Round-17: combine the two proven winners. R15/R16 refuted intra-block
// counted-vmcnt pipelining (cross-block TLP hides the stage->compute drain
// better than explicit overlap + extra barriers). So: R12's single-shot
// TR=16 tile at 8 blocks/CU (max cross-block drain-hiding; LDS 19.7 KB)
// + R14's rolling 3-read conflict-free compute (R12 paid 5 b128/row)
// + halo columns staged by one width-4 global_load_lds DMA per side.

#define NX 4096
#define NY 4096
#define TR 16                  // output rows per tile
#define HR (TR + 2)            // staged rows
#define TC 256                 // cols per tile
#define LSTRIDE 264            // LDS row stride in floats
#define HOFF (HR * LSTRIDE)    // halo arrays: left at +0, right at +64
#define BUF_FLOATS (HOFF + 128)

typedef float float4v __attribute__((ext_vector_type(4)));

__device__ __forceinline__ void row_to_lds(const float* g, float* l) {
    __builtin_amdgcn_global_load_lds(
        (const __attribute__((address_space(1))) uint32_t*)g,
        (__attribute__((address_space(3))) uint32_t*)l, 16, 0, 0);
}
__device__ __forceinline__ void sc_to_lds(const float* g, float* l) {
    __builtin_amdgcn_global_load_lds(
        (const __attribute__((address_space(1))) uint32_t*)g,
        (__attribute__((address_space(3))) uint32_t*)l, 4, 0, 0);
}

__global__ __launch_bounds__(256, 8) void flux_stencil_kernel(
    const float* __restrict__ u,
    const float* __restrict__ D_eff,
    const float* __restrict__ dv,
    const float* __restrict__ st,
    float* __restrict__ out)
{
    __shared__ float s[BUF_FLOATS];     // 19,520 B -> 8 blocks/CU

    const float D  = D_eff[0];
    const float s0 = st[0];
    const float s1 = st[1];
    const float k1 = D * s0;            // neighbor coefficient
    const float k4 = 4.0f * D * s1;     // center coefficient
    const float dvUp = dv[0], dvDn = dv[1], dvL = dv[2], dvR = dv[3];

    // XCD swizzle (XCD = b%8): XCD X gets bands [32X, 32X+32), 16 col-tiles.
    const int b    = blockIdx.x;               // [0,4096)
    const int X    = b & 7;
    const int r    = b >> 3;                   // [0,512)
    const int ct   = r & 15;                   // col-tile [0,16)
    const int band = X * 32 + (r >> 4);        // [0,256)
    const int i0   = band * TR;
    const int j0   = ct * TC;

    const int t    = threadIdx.x;
    const int w    = t >> 6;                   // wave [0,4)
    const int lane = t & 63;

    const bool lEdgeCol = (j0 == 0);
    const bool rEdgeCol = (j0 + TC == NY);
    const bool topE     = (i0 == 0);
    const bool botE     = (i0 + TR == NX);

    // ---- stage: 18 rows (waves 5/5/4/4) + 2 halo-column DMAs ----
    for (int k = w; k < HR; k += 4) {
        int gr = i0 + k - 1;
        gr = gr < 0 ? 0 : (gr > NX - 1 ? NX - 1 : gr);
        row_to_lds(u + (size_t)gr * NY + j0 + 4 * lane, &s[k * LSTRIDE]);
    }
    if (w == 2) {                              // left halo column
        const int gr  = i0 + (lane < TR ? lane : TR - 1);
        const int col = lEdgeCol ? 0 : j0 - 1;
        sc_to_lds(u + (size_t)gr * NY + col, &s[HOFF]);
    }
    if (w == 3) {                              // right halo column
        const int gr  = i0 + (lane < TR ? lane : TR - 1);
        const int col = rEdgeCol ? NY - 1 : j0 + TC;
        sc_to_lds(u + (size_t)gr * NY + col, &s[HOFF + 64]);
    }

    __syncthreads();   // drains DMA; cross-block TLP (8 blocks/CU) hides it

    // ---- compute: wave w owns rows w*4 .. w*4+3 (rolling 3-read) ----
    const int cOff = 4 * lane;
    const int lOff = (lane == 0) ? 0 : cOff - 4;   // lane0: dummy, selected out
    const int rOff = cOff + 4;                     // lane63: pad, selected out
    const int rrB  = w * 4;                        // first row of this wave
    const int kB   = rrB + 1;                      // its LDS row index

    float4v up = *(const float4v*)&s[(kB - 1) * LSTRIDE + cOff];
    float4v c  = *(const float4v*)&s[kB * LSTRIDE + cOff];
    const float4v lv0 = *(const float4v*)&s[kB * LSTRIDE + lOff];
    const float4v rv0 = *(const float4v*)&s[kB * LSTRIDE + rOff];
    float lft = (lane == 0)  ? (lEdgeCol ? dvL : s[HOFF + rrB])      : lv0.w;
    float rgt = (lane == 63) ? (rEdgeCol ? dvR : s[HOFF + 64 + rrB]) : rv0.x;
    if (topE && w == 0) { up.x = dvUp; up.y = dvUp; up.z = dvUp; up.w = dvUp; }

    #pragma unroll
    for (int rr4 = 0; rr4 < 4; ++rr4) {
        const int rr = rrB + rr4;                  // row in tile [0,16)
        const int k  = rr + 1;                     // LDS row index
        const float* nrow = &s[(k + 1) * LSTRIDE];

        float4v dn        = *(const float4v*)(nrow + cOff);
        const float4v dnl = *(const float4v*)(nrow + lOff);
        const float4v dnr = *(const float4v*)(nrow + rOff);

        if (botE && rr == TR - 1) { dn.x = dvDn; dn.y = dvDn; dn.z = dvDn; dn.w = dvDn; }

        float4v o;
        o.x = k1 * (up.x + dn.x + lft + c.y) + k4 * c.x;
        o.y = k1 * (up.y + dn.y + c.x + c.z) + k4 * c.y;
        o.z = k1 * (up.z + dn.z + c.y + c.w) + k4 * c.z;
        o.w = k1 * (up.w + dn.w + c.z + rgt) + k4 * c.w;

        *(float4v*)(out + (size_t)(i0 + rr) * NY + j0 + cOff) = o;

        up  = c;
        c   = dn;
        lft = (lane == 0)  ? (lEdgeCol ? dvL : s[HOFF + rr + 1])      : dnl.w;
        rgt = (lane == 63) ? (rEdgeCol ? dvR : s[HOFF + 64 + rr + 1]) : dnr.x;
    }
}

extern "C" void kernel_launch(void* const* d_in, const int* in_sizes, int n_in,
                              void* d_out, int out_size, void* d_ws, size_t ws_size,
                              hipStream_t stream) {
    const float* u_main    = (const float*)d_in[0];
    // d_in[1] = u_coupled (unused)
    const float* D_eff     = (const float*)d_in[2];
    const float* dirichlet = (const float*)d_in[3];
    const float* stencil   = (const float*)d_in[4];
    // d_in[5] = t (unused)
    float* outp = (float*)d_out;

    // 256 bands x 16 col-tiles = 4096 blocks of 256 threads, 8 blocks/CU
    const int grid  = 4096;
    const int block = 256;

    flux_stencil_kernel<<<grid, block, 0, stream>>>(u_main, D_eff, dirichlet, stencil, outp);
}